// Round 10
// baseline (416.347 us; speedup 1.0000x reference)
//
#include <hip/hip_runtime.h>

#define LEAF   16384
#define NNODE  (2*LEAF-1)
#define LATENT 256
#define HIDDEN 512
#define SYM    64
#define BOX    128

using half8 = __attribute__((ext_vector_type(8))) _Float16;
using f32x4 = __attribute__((ext_vector_type(4))) float;

__device__ __forceinline__ f32x4 mfma16h(half8 a, half8 b, f32x4 c){
    return __builtin_amdgcn_mfma_f32_16x16x32_f16(a, b, c, 0, 0, 0);
}

// agent-coherent 16B load (2 x 8B relaxed agent atomics -> global_load sc1,
// reads LLC, immune to stale L2; no acquire fence needed for these)
__device__ __forceinline__ half8 ldc16(const _Float16* p){
    union { unsigned long long u[2]; half8 h; } c;
    c.u[0] = __hip_atomic_load((const unsigned long long*)p,     __ATOMIC_RELAXED, __HIP_MEMORY_SCOPE_AGENT);
    c.u[1] = __hip_atomic_load((const unsigned long long*)p + 1, __ATOMIC_RELAXED, __HIP_MEMORY_SCOPE_AGENT);
    return c.h;
}

// ---------------------------------------------------------------------------
// Fused weight pack (fp16, MFMA B-fragment order), one dispatch for all 5.
// ---------------------------------------------------------------------------
__global__ void pack_all(const float* __restrict__ Wl, const float* __restrict__ Wr,
                         const float* __restrict__ Wsl, const float* __restrict__ Wsr,
                         const float* __restrict__ W2, const float* __restrict__ Ws2,
                         const float* __restrict__ Wb,
                         _Float16* __restrict__ wcat, _Float16* __restrict__ wscat,
                         _Float16* __restrict__ w2p, _Float16* __restrict__ ws2p,
                         _Float16* __restrict__ wbp)
{
    int g = blockIdx.x*256 + threadIdx.x;
    const float *A, *B; _Float16* pk; int Ksplit, N, KS, t;
    if (g < 262144)      { t = g;          A=Wl;  B=Wr;  pk=wcat;  Ksplit=256; N=512; KS=16; }
    else if (g < 425984) { t = g-262144;   A=Wsl; B=Wsr; pk=wscat; Ksplit=256; N=512; KS=10; }
    else if (g < 557056) { t = g-425984;   A=W2;  B=W2;  pk=w2p;   Ksplit=512; N=256; KS=16; }
    else if (g < 688128) { t = g-557056;   A=Ws2; B=Ws2; pk=ws2p;  Ksplit=512; N=256; KS=16; }
    else if (g < 720896) { t = g-688128;   A=Wb;  B=Wb;  pk=wbp;   Ksplit=128; N=256; KS=4;  }
    else return;
    int j = t & 7, l = (t>>3)&63, tile = (t>>9)&3;
    int rest = t >> 11;
    int ks = rest % KS, cb = rest / KS;
    int k   = ks*32 + ((l>>4)*8) + j;
    int col = cb*64 + tile*16 + (l&15);
    float wv = (k < Ksplit) ? A[(size_t)k*N + col] : B[(size_t)(k-Ksplit)*N + col];
    pk[((size_t)(cb*KS + ks)*4 + tile)*512 + (size_t)l*8 + j] = (_Float16)wv;
}

// ---------------------------------------------------------------------------
// Leaf via MFMA
// ---------------------------------------------------------------------------
__global__ __launch_bounds__(256) void leaf_mfma_kernel(
    const float* __restrict__ shape, const _Float16* __restrict__ wbpk,
    const float* __restrict__ bb, _Float16* __restrict__ hh)
{
    const int t = threadIdx.x, lane = t & 63, w = t >> 6;
    const int r0 = blockIdx.x * 64;
    const int m = r0 + w*16 + (lane & 15);

    half8 A[4];
    #pragma unroll
    for (int ks = 0; ks < 4; ++ks) {
        #pragma unroll
        for (int e = 0; e < 8; ++e) {
            int k = ks*32 + (lane >> 4)*8 + e;
            A[ks][e] = (_Float16)shape[(size_t)k*LEAF + m];
        }
    }

    for (int cb = 0; cb < 4; ++cb) {
        f32x4 acc[4];
        #pragma unroll
        for (int c = 0; c < 4; ++c) acc[c] = (f32x4){0.f,0.f,0.f,0.f};
        #pragma unroll
        for (int ks = 0; ks < 4; ++ks) {
            const _Float16* pb = wbpk + (size_t)((cb*4 + ks)*4)*512;
            #pragma unroll
            for (int tile = 0; tile < 4; ++tile) {
                half8 B = *(const half8*)(pb + tile*512 + lane*8);
                acc[tile] = mfma16h(A[ks], B, acc[tile]);
            }
        }
        #pragma unroll
        for (int tile = 0; tile < 4; ++tile) {
            int col = cb*64 + tile*16 + (lane & 15);
            float bv = bb[col];
            #pragma unroll
            for (int r = 0; r < 4; ++r) {
                int row = r0 + w*16 + (lane >> 4)*4 + r;
                hh[(size_t)row*256 + col] = (_Float16)tanhf(acc[tile][r] + bv);
            }
        }
    }
}

// ---------------------------------------------------------------------------
// k1 body (dispatch path)
// ---------------------------------------------------------------------------
template<int NSUB>
__device__ __forceinline__ void k1_body(
    int rb, int cb, int start, int n,
    const _Float16* __restrict__ hh, const float* __restrict__ param,
    const _Float16* __restrict__ wcatpk, const _Float16* __restrict__ wscatpk,
    const float* __restrict__ b1, const float* __restrict__ bs1,
    _Float16* __restrict__ U, _Float16* __restrict__ V)
{
    __shared__ __align__(16) _Float16 ldsB1[2*2048];
    const int t = threadIdx.x, lane = t & 63, w = t >> 6;
    const bool isV = cb >= 8;
    const int cbl = isV ? cb - 8 : cb;
    const int KS  = isV ? 10 : 16;
    const _Float16* pk = (isV ? wscatpk : wcatpk) + (size_t)cbl * KS * 2048;
    const int row0  = rb * NSUB * 64;
    const int cbase = 2 * (start - LEAF);

    f32x4 acc[NSUB][4];
    #pragma unroll
    for (int s = 0; s < NSUB; ++s)
        #pragma unroll
        for (int c = 0; c < 4; ++c) acc[s][c] = (f32x4){0.f,0.f,0.f,0.f};

    *(half8*)(ldsB1 + t*8) = *(const half8*)(pk + (size_t)t*8);
    __syncthreads();

    for (int ks = 0; ks < KS; ++ks) {
        const bool hasNext = ks + 1 < KS;
        half8 stg;
        if (hasNext) stg = *(const half8*)(pk + (size_t)(ks+1)*2048 + (size_t)t*8);
        half8 A[NSUB];
        #pragma unroll
        for (int s = 0; s < NSUB; ++s) {
            int m = row0 + (s*4 + w)*16 + (lane & 15);
            if (m >= n) m = n - 1;
            if (!isV || ks < 8) {
                int node = cbase + 2*m + (ks >= 8 ? 1 : 0);
                A[s] = *(const half8*)(hh + (size_t)node*256 + (size_t)(ks & 7)*32 + ((lane >> 4)*8));
            } else {
                const float* pp = param + (size_t)(cbase + 2*m)*64 + (ks - 8)*32 + (lane >> 4)*8;
                float4 p0 = *(const float4*)pp;
                float4 p1 = *(const float4*)(pp + 4);
                A[s][0]=(_Float16)p0.x; A[s][1]=(_Float16)p0.y; A[s][2]=(_Float16)p0.z; A[s][3]=(_Float16)p0.w;
                A[s][4]=(_Float16)p1.x; A[s][5]=(_Float16)p1.y; A[s][6]=(_Float16)p1.z; A[s][7]=(_Float16)p1.w;
            }
        }
        const _Float16* lb = ldsB1 + (ks & 1)*2048;
        #pragma unroll
        for (int tile = 0; tile < 4; ++tile) {
            half8 Bh = *(const half8*)(lb + tile*512 + lane*8);
            #pragma unroll
            for (int s = 0; s < NSUB; ++s)
                acc[s][tile] = mfma16h(A[s], Bh, acc[s][tile]);
        }
        if (hasNext)
            *(half8*)(ldsB1 + ((ks+1) & 1)*2048 + t*8) = stg;
        __syncthreads();
    }

    const float* bias = isV ? bs1 : b1;
    _Float16* o = isV ? V : U;
    #pragma unroll
    for (int s = 0; s < NSUB; ++s) {
        #pragma unroll
        for (int tile = 0; tile < 4; ++tile) {
            int col = cbl*64 + tile*16 + (lane & 15);
            float bv = bias[col];
            #pragma unroll
            for (int r = 0; r < 4; ++r) {
                int m = row0 + (s*4 + w)*16 + (lane >> 4)*4 + r;
                if (m < n)
                    o[(size_t)m*512 + col] = (_Float16)tanhf(acc[s][tile][r] + bv);
            }
        }
    }
}

// ---------------------------------------------------------------------------
// k2 body (dispatch path)
// ---------------------------------------------------------------------------
template<int NSUB>
__device__ __forceinline__ void k2_body(
    int rb, int cb, int start, int n,
    const _Float16* __restrict__ U, const _Float16* __restrict__ V,
    const int* __restrict__ kids,
    const _Float16* __restrict__ w2pk, const _Float16* __restrict__ ws2pk,
    const float* __restrict__ b2, const float* __restrict__ bs2,
    _Float16* __restrict__ hh)
{
    __shared__ __align__(16) _Float16 ldsB2[2*2048];
    const int t = threadIdx.x, lane = t & 63, w = t >> 6;
    const bool isSym = cb >= 4;
    const int cbl = isSym ? cb - 4 : cb;
    const _Float16* pk = (isSym ? ws2pk : w2pk) + (size_t)cbl * 16 * 2048;
    const _Float16* Asrc = isSym ? V : U;
    const int row0 = rb * NSUB * 64;

    f32x4 acc[NSUB][4];
    #pragma unroll
    for (int s = 0; s < NSUB; ++s)
        #pragma unroll
        for (int c = 0; c < 4; ++c) acc[s][c] = (f32x4){0.f,0.f,0.f,0.f};

    *(half8*)(ldsB2 + t*8) = *(const half8*)(pk + (size_t)t*8);
    __syncthreads();

    for (int ks = 0; ks < 16; ++ks) {
        const bool hasNext = ks + 1 < 16;
        half8 stg;
        if (hasNext) stg = *(const half8*)(pk + (size_t)(ks+1)*2048 + (size_t)t*8);
        half8 A[NSUB];
        #pragma unroll
        for (int s = 0; s < NSUB; ++s) {
            int m = row0 + (s*4 + w)*16 + (lane & 15);
            if (m >= n) m = n - 1;
            A[s] = *(const half8*)(Asrc + (size_t)m*512 + (size_t)ks*32 + ((lane >> 4)*8));
        }
        const _Float16* lb = ldsB2 + (ks & 1)*2048;
        #pragma unroll
        for (int tile = 0; tile < 4; ++tile) {
            half8 Bh = *(const half8*)(lb + tile*512 + lane*8);
            #pragma unroll
            for (int s = 0; s < NSUB; ++s)
                acc[s][tile] = mfma16h(A[s], Bh, acc[s][tile]);
        }
        if (hasNext)
            *(half8*)(ldsB2 + ((ks+1) & 1)*2048 + t*8) = stg;
        __syncthreads();
    }

    const float* bias = isSym ? bs2 : b2;
    const int want = isSym ? 1 : 0;
    #pragma unroll
    for (int s = 0; s < NSUB; ++s) {
        #pragma unroll
        for (int tile = 0; tile < 4; ++tile) {
            int col = cbl*64 + tile*16 + (lane & 15);
            float bv = bias[col];
            #pragma unroll
            for (int r = 0; r < 4; ++r) {
                int m = row0 + (s*4 + w)*16 + (lane >> 4)*4 + r;
                if (m < n && kids[3*(start + m) + 2] == want)
                    hh[(size_t)(start + m)*256 + col] = (_Float16)tanhf(acc[s][tile][r] + bv);
            }
        }
    }
}

template<int NSUB>
__global__ __launch_bounds__(256) void k1_kernel(
    const _Float16* __restrict__ hh, const float* __restrict__ param,
    const _Float16* __restrict__ wcatpk, const _Float16* __restrict__ wscatpk,
    const float* __restrict__ b1, const float* __restrict__ bs1,
    _Float16* __restrict__ U, _Float16* __restrict__ V, int start, int n)
{
    k1_body<NSUB>(blockIdx.x, blockIdx.y, start, n, hh, param, wcatpk, wscatpk, b1, bs1, U, V);
}

template<int NSUB>
__global__ __launch_bounds__(256) void k2_kernel(
    const _Float16* __restrict__ U, const _Float16* __restrict__ V,
    const int* __restrict__ kids,
    const _Float16* __restrict__ w2pk, const _Float16* __restrict__ ws2pk,
    const float* __restrict__ b2, const float* __restrict__ bs2,
    _Float16* __restrict__ hh, int start, int n)
{
    k2_body<NSUB>(blockIdx.x, blockIdx.y, start, n, U, V, kids, w2pk, ws2pk, b2, bs2, hh);
}

// ---------------------------------------------------------------------------
// Tail bodies: weights in LDS; cross-phase data read via sc1 (agent) loads,
// ALL A-fragments preloaded to registers before the MFMA chain (latency ILP).
// ---------------------------------------------------------------------------
__device__ __forceinline__ void k1_tail(
    int rb, int cb, int start, int n,
    const _Float16* __restrict__ hh, const float* __restrict__ param,
    const _Float16* wlds, f32x4 bv,
    _Float16* __restrict__ U, _Float16* __restrict__ V)
{
    const int t = threadIdx.x, lane = t & 63, w = t >> 6;
    const bool isV = cb >= 8;
    const int cbl = isV ? cb - 8 : cb;
    const int row0  = rb * 64;
    const int cbase = 2 * (start - LEAF);

    int m = row0 + w*16 + (lane & 15);
    if (m >= n) m = n - 1;

    f32x4 acc[4];
    #pragma unroll
    for (int c = 0; c < 4; ++c) acc[c] = (f32x4){0.f,0.f,0.f,0.f};

    if (!isV) {
        half8 A[16];
        #pragma unroll
        for (int ks = 0; ks < 16; ++ks) {
            int node = cbase + 2*m + (ks >= 8 ? 1 : 0);
            A[ks] = ldc16(hh + (size_t)node*256 + (size_t)(ks & 7)*32 + ((lane >> 4)*8));
        }
        #pragma unroll
        for (int ks = 0; ks < 16; ++ks) {
            const _Float16* lb = wlds + ks*2048;
            #pragma unroll
            for (int tile = 0; tile < 4; ++tile) {
                half8 Bh = *(const half8*)(lb + tile*512 + lane*8);
                acc[tile] = mfma16h(A[ks], Bh, acc[tile]);
            }
        }
    } else {
        half8 A[10];
        #pragma unroll
        for (int ks = 0; ks < 8; ++ks)
            A[ks] = ldc16(hh + (size_t)(cbase + 2*m)*256 + (size_t)ks*32 + ((lane >> 4)*8));
        #pragma unroll
        for (int ks = 8; ks < 10; ++ks) {
            const float* pp = param + (size_t)(cbase + 2*m)*64 + (ks - 8)*32 + (lane >> 4)*8;
            float4 p0 = *(const float4*)pp;
            float4 p1 = *(const float4*)(pp + 4);
            A[ks][0]=(_Float16)p0.x; A[ks][1]=(_Float16)p0.y; A[ks][2]=(_Float16)p0.z; A[ks][3]=(_Float16)p0.w;
            A[ks][4]=(_Float16)p1.x; A[ks][5]=(_Float16)p1.y; A[ks][6]=(_Float16)p1.z; A[ks][7]=(_Float16)p1.w;
        }
        #pragma unroll
        for (int ks = 0; ks < 10; ++ks) {
            const _Float16* lb = wlds + ks*2048;
            #pragma unroll
            for (int tile = 0; tile < 4; ++tile) {
                half8 Bh = *(const half8*)(lb + tile*512 + lane*8);
                acc[tile] = mfma16h(A[ks], Bh, acc[tile]);
            }
        }
    }

    _Float16* o = isV ? V : U;
    #pragma unroll
    for (int tile = 0; tile < 4; ++tile) {
        int col = cbl*64 + tile*16 + (lane & 15);
        #pragma unroll
        for (int r = 0; r < 4; ++r) {
            int mm = row0 + w*16 + (lane >> 4)*4 + r;
            if (mm < n)
                o[(size_t)mm*512 + col] = (_Float16)tanhf(acc[tile][r] + bv[tile]);
        }
    }
}

__device__ __forceinline__ void k2_tail(
    int rb, int cb, int start, int n,
    const _Float16* __restrict__ U, const _Float16* __restrict__ V,
    const int* __restrict__ kids,
    const _Float16* wlds, f32x4 bv,
    _Float16* __restrict__ hh)
{
    const int t = threadIdx.x, lane = t & 63, w = t >> 6;
    const bool isSym = cb >= 4;
    const int cbl = isSym ? cb - 4 : cb;
    const _Float16* Asrc = isSym ? V : U;
    const int row0 = rb * 64;

    int m = row0 + w*16 + (lane & 15);
    if (m >= n) m = n - 1;

    half8 A[16];
    #pragma unroll
    for (int ks = 0; ks < 16; ++ks)
        A[ks] = ldc16(Asrc + (size_t)m*512 + (size_t)ks*32 + ((lane >> 4)*8));

    f32x4 acc[4];
    #pragma unroll
    for (int c = 0; c < 4; ++c) acc[c] = (f32x4){0.f,0.f,0.f,0.f};
    #pragma unroll
    for (int ks = 0; ks < 16; ++ks) {
        const _Float16* lb = wlds + ks*2048;
        #pragma unroll
        for (int tile = 0; tile < 4; ++tile) {
            half8 Bh = *(const half8*)(lb + tile*512 + lane*8);
            acc[tile] = mfma16h(A[ks], Bh, acc[tile]);
        }
    }

    const int want = isSym ? 1 : 0;
    #pragma unroll
    for (int tile = 0; tile < 4; ++tile) {
        int col = cbl*64 + tile*16 + (lane & 15);
        #pragma unroll
        for (int r = 0; r < 4; ++r) {
            int mm = row0 + w*16 + (lane >> 4)*4 + r;
            if (mm < n && kids[3*(start + mm) + 2] == want)
                hh[(size_t)(start + mm)*256 + col] = (_Float16)tanhf(acc[tile][r] + bv[tile]);
        }
    }
}

// ---------------------------------------------------------------------------
// Flag barrier: writers release (waitcnt+wbl2), non-writers relaxed store.
// NO acquire fence: readers use sc1 loads (LLC-coherent). Workgroup fence
// is compiler-ordering only.
// ---------------------------------------------------------------------------
#define TAILG 48
__device__ __forceinline__ void fbar(unsigned* flags, unsigned tgt, bool wrote)
{
    __syncthreads();
    if (threadIdx.x == 0) {
        if (wrote)
            __hip_atomic_store(flags + blockIdx.x*16, tgt, __ATOMIC_RELEASE, __HIP_MEMORY_SCOPE_AGENT);
        else
            __hip_atomic_store(flags + blockIdx.x*16, tgt, __ATOMIC_RELAXED, __HIP_MEMORY_SCOPE_AGENT);
    }
    if (threadIdx.x < TAILG) {
        while (__hip_atomic_load(flags + threadIdx.x*16, __ATOMIC_RELAXED, __HIP_MEMORY_SCOPE_AGENT) < tgt)
            __builtin_amdgcn_s_sleep(1);
    }
    __syncthreads();
    __builtin_amdgcn_fence(__ATOMIC_ACQUIRE, "workgroup");
}

// ---------------------------------------------------------------------------
// Tail: levels n<=1024 persistent, 48 blocks.
// Blocks 0-31: k1 (16 col-slices x 2 row-halves). 32-47: k2 (8 x 2).
// ---------------------------------------------------------------------------
__global__ __launch_bounds__(256) void tail_kernel(
    _Float16* __restrict__ hh, const float* __restrict__ param,
    const _Float16* __restrict__ wcatpk, const _Float16* __restrict__ wscatpk,
    const float* __restrict__ b1, const float* __restrict__ bs1,
    _Float16* __restrict__ U, _Float16* __restrict__ V,
    const int* __restrict__ kids,
    const _Float16* __restrict__ w2pk, const _Float16* __restrict__ ws2pk,
    const float* __restrict__ b2, const float* __restrict__ bs2,
    unsigned* __restrict__ flags, float* __restrict__ out)
{
    __shared__ __align__(16) _Float16 wlds[16*2048];   // 64 KB
    const int b = blockIdx.x;          // 0..47
    const int t = threadIdx.x, lane = t & 63;
    const bool isK1 = b < 32;
    int cb, rh;
    const _Float16* src;
    const float* bias;
    int nh;
    if (isK1) {
        cb = b & 15; rh = b >> 4;
        if (cb < 8) { src = wcatpk  + (size_t)cb*16*2048;     nh = 16*256; bias = b1; }
        else        { src = wscatpk + (size_t)(cb-8)*10*2048; nh = 10*256; bias = bs1; }
    } else {
        int i = b - 32; cb = i & 7; rh = i >> 3;
        if (cb < 4) { src = w2pk  + (size_t)cb*16*2048;     bias = b2; }
        else        { src = ws2pk + (size_t)(cb-4)*16*2048; bias = bs2; }
        nh = 16*256;
    }
    for (int i = t; i < nh; i += 256)
        *(half8*)(wlds + (size_t)i*8) = *(const half8*)(src + (size_t)i*8);

    f32x4 bv;
    {
        int cbl = isK1 ? (cb & 7) : (cb & 3);
        #pragma unroll
        for (int tile = 0; tile < 4; ++tile)
            bv[tile] = bias[cbl*64 + tile*16 + (lane & 15)];
    }
    __syncthreads();

    unsigned tgt = 0;
    int start = LEAF + 8192 + 4096 + 2048;   // 30720, first tail level n=1024
    for (int n = 1024; n >= 1; n >>= 1) {
        int rt = (n + 63) >> 6;
        if (isK1) {
            for (int r = rh; r < rt; r += 2)
                k1_tail(r, cb, start, n, hh, param, wlds, bv, U, V);
        }
        ++tgt; fbar(flags, tgt, isK1);
        if (!isK1) {
            for (int r = rh; r < rt; r += 2)
                k2_tail(r, cb, start, n, U, V, kids, wlds, bv, hh);
        }
        ++tgt; fbar(flags, tgt, !isK1);
        start += n;
    }
    if (b == 0 && t < 32) {
        half8 v = ldc16(hh + (size_t)(NNODE - 1)*256 + t*8);
        #pragma unroll
        for (int e = 0; e < 8; ++e)
            out[t*8 + e] = (float)v[e];
    }
}

extern "C" void kernel_launch(void* const* d_in, const int* in_sizes, int n_in,
                              void* d_out, int out_size, void* d_ws, size_t ws_size,
                              hipStream_t stream) {
    const int*   kids  = (const int*)  d_in[0];
    const float* shape = (const float*)d_in[1];
    const float* param = (const float*)d_in[2];
    const float* Wb    = (const float*)d_in[3];
    const float* bb    = (const float*)d_in[4];
    const float* Wl    = (const float*)d_in[5];
    const float* Wr    = (const float*)d_in[6];
    const float* b1    = (const float*)d_in[7];
    const float* W2    = (const float*)d_in[8];
    const float* b2    = (const float*)d_in[9];
    const float* Wsl   = (const float*)d_in[10];
    const float* Wsr   = (const float*)d_in[11];
    const float* bs1   = (const float*)d_in[12];
    const float* Ws2   = (const float*)d_in[13];
    const float* bs2   = (const float*)d_in[14];
    float* out = (float*)d_out;

    char* ws = (char*)d_ws;
    _Float16* hh      = (_Float16*)(ws + 0);          // 16.8MB
    _Float16* U       = (_Float16*)(ws + 16777216);   // 8.4MB
    _Float16* V       = (_Float16*)(ws + 25165824);   // 8.4MB
    _Float16* wcatpk  = (_Float16*)(ws + 33554432);   // 512KB
    _Float16* wscatpk = (_Float16*)(ws + 34078720);   // 320KB
    _Float16* w2pk    = (_Float16*)(ws + 34406400);   // 256KB
    _Float16* ws2pk   = (_Float16*)(ws + 34668544);   // 256KB
    _Float16* wbpk    = (_Float16*)(ws + 34930688);   // 64KB
    unsigned* flags   = (unsigned*)(ws + 34996224);   // 48*64B

    hipMemsetAsync(flags, 0, TAILG*64, stream);

    pack_all<<<2816, 256, 0, stream>>>(Wl, Wr, Wsl, Wsr, W2, Ws2, Wb,
                                       wcatpk, wscatpk, w2pk, ws2pk, wbpk);

    leaf_mfma_kernel<<<LEAF/64, 256, 0, stream>>>(shape, wbpk, bb, hh);

    int start = LEAF;
    for (int n = 8192; n >= 2048; n >>= 1) {
        if (n == 8192) {
            k1_kernel<2><<<dim3(n/128, 16), 256, 0, stream>>>(hh, param, wcatpk, wscatpk,
                                                              b1, bs1, U, V, start, n);
        } else {
            k1_kernel<1><<<dim3(n/64, 16), 256, 0, stream>>>(hh, param, wcatpk, wscatpk,
                                                             b1, bs1, U, V, start, n);
        }
        k2_kernel<1><<<dim3(n/64, 8), 256, 0, stream>>>(U, V, kids, w2pk, ws2pk,
                                                        b2, bs2, hh, start, n);
        start += n;
    }

    tail_kernel<<<TAILG, 256, 0, stream>>>(hh, param, wcatpk, wscatpk, b1, bs1,
                                           U, V, kids, w2pk, ws2pk, b2, bs2, flags, out);
}

// Round 12
// 344.014 us; speedup vs baseline: 1.2103x; 1.2103x over previous
//
#include <hip/hip_runtime.h>

#define LEAF   16384
#define NNODE  (2*LEAF-1)
#define LATENT 256
#define HIDDEN 512
#define SYM    64
#define BOX    128

using half8 = __attribute__((ext_vector_type(8))) _Float16;
using f32x4 = __attribute__((ext_vector_type(4))) float;

__device__ __forceinline__ f32x4 mfma16h(half8 a, half8 b, f32x4 c){
    return __builtin_amdgcn_mfma_f32_16x16x32_f16(a, b, c, 0, 0, 0);
}

// ---------------------------------------------------------------------------
// Fused weight pack (fp16, MFMA B-fragment order), one dispatch for all 5.
// ---------------------------------------------------------------------------
__global__ void pack_all(const float* __restrict__ Wl, const float* __restrict__ Wr,
                         const float* __restrict__ Wsl, const float* __restrict__ Wsr,
                         const float* __restrict__ W2, const float* __restrict__ Ws2,
                         const float* __restrict__ Wb,
                         _Float16* __restrict__ wcat, _Float16* __restrict__ wscat,
                         _Float16* __restrict__ w2p, _Float16* __restrict__ ws2p,
                         _Float16* __restrict__ wbp)
{
    int g = blockIdx.x*256 + threadIdx.x;
    const float *A, *B; _Float16* pk; int Ksplit, N, KS, t;
    if (g < 262144)      { t = g;          A=Wl;  B=Wr;  pk=wcat;  Ksplit=256; N=512; KS=16; }
    else if (g < 425984) { t = g-262144;   A=Wsl; B=Wsr; pk=wscat; Ksplit=256; N=512; KS=10; }
    else if (g < 557056) { t = g-425984;   A=W2;  B=W2;  pk=w2p;   Ksplit=512; N=256; KS=16; }
    else if (g < 688128) { t = g-557056;   A=Ws2; B=Ws2; pk=ws2p;  Ksplit=512; N=256; KS=16; }
    else if (g < 720896) { t = g-688128;   A=Wb;  B=Wb;  pk=wbp;   Ksplit=128; N=256; KS=4;  }
    else return;
    int j = t & 7, l = (t>>3)&63, tile = (t>>9)&3;
    int rest = t >> 11;
    int ks = rest % KS, cb = rest / KS;
    int k   = ks*32 + ((l>>4)*8) + j;
    int col = cb*64 + tile*16 + (l&15);
    float wv = (k < Ksplit) ? A[(size_t)k*N + col] : B[(size_t)(k-Ksplit)*N + col];
    pk[((size_t)(cb*KS + ks)*4 + tile)*512 + (size_t)l*8 + j] = (_Float16)wv;
}

// ---------------------------------------------------------------------------
// Leaf via MFMA
// ---------------------------------------------------------------------------
__global__ __launch_bounds__(256) void leaf_mfma_kernel(
    const float* __restrict__ shape, const _Float16* __restrict__ wbpk,
    const float* __restrict__ bb, _Float16* __restrict__ hh)
{
    const int t = threadIdx.x, lane = t & 63, w = t >> 6;
    const int r0 = blockIdx.x * 64;
    const int m = r0 + w*16 + (lane & 15);

    half8 A[4];
    #pragma unroll
    for (int ks = 0; ks < 4; ++ks) {
        #pragma unroll
        for (int e = 0; e < 8; ++e) {
            int k = ks*32 + (lane >> 4)*8 + e;
            A[ks][e] = (_Float16)shape[(size_t)k*LEAF + m];
        }
    }

    for (int cb = 0; cb < 4; ++cb) {
        f32x4 acc[4];
        #pragma unroll
        for (int c = 0; c < 4; ++c) acc[c] = (f32x4){0.f,0.f,0.f,0.f};
        #pragma unroll
        for (int ks = 0; ks < 4; ++ks) {
            const _Float16* pb = wbpk + (size_t)((cb*4 + ks)*4)*512;
            #pragma unroll
            for (int tile = 0; tile < 4; ++tile) {
                half8 B = *(const half8*)(pb + tile*512 + lane*8);
                acc[tile] = mfma16h(A[ks], B, acc[tile]);
            }
        }
        #pragma unroll
        for (int tile = 0; tile < 4; ++tile) {
            int col = cb*64 + tile*16 + (lane & 15);
            float bv = bb[col];
            #pragma unroll
            for (int r = 0; r < 4; ++r) {
                int row = r0 + w*16 + (lane >> 4)*4 + r;
                hh[(size_t)row*256 + col] = (_Float16)tanhf(acc[tile][r] + bv);
            }
        }
    }
}

// ---------------------------------------------------------------------------
// k1 body (dispatch path)
// ---------------------------------------------------------------------------
template<int NSUB>
__device__ __forceinline__ void k1_body(
    int rb, int cb, int start, int n,
    const _Float16* __restrict__ hh, const float* __restrict__ param,
    const _Float16* __restrict__ wcatpk, const _Float16* __restrict__ wscatpk,
    const float* __restrict__ b1, const float* __restrict__ bs1,
    _Float16* __restrict__ U, _Float16* __restrict__ V)
{
    __shared__ __align__(16) _Float16 ldsB1[2*2048];
    const int t = threadIdx.x, lane = t & 63, w = t >> 6;
    const bool isV = cb >= 8;
    const int cbl = isV ? cb - 8 : cb;
    const int KS  = isV ? 10 : 16;
    const _Float16* pk = (isV ? wscatpk : wcatpk) + (size_t)cbl * KS * 2048;
    const int row0  = rb * NSUB * 64;
    const int cbase = 2 * (start - LEAF);

    f32x4 acc[NSUB][4];
    #pragma unroll
    for (int s = 0; s < NSUB; ++s)
        #pragma unroll
        for (int c = 0; c < 4; ++c) acc[s][c] = (f32x4){0.f,0.f,0.f,0.f};

    *(half8*)(ldsB1 + t*8) = *(const half8*)(pk + (size_t)t*8);
    __syncthreads();

    for (int ks = 0; ks < KS; ++ks) {
        const bool hasNext = ks + 1 < KS;
        half8 stg;
        if (hasNext) stg = *(const half8*)(pk + (size_t)(ks+1)*2048 + (size_t)t*8);
        half8 A[NSUB];
        #pragma unroll
        for (int s = 0; s < NSUB; ++s) {
            int m = row0 + (s*4 + w)*16 + (lane & 15);
            if (m >= n) m = n - 1;
            if (!isV || ks < 8) {
                int node = cbase + 2*m + (ks >= 8 ? 1 : 0);
                A[s] = *(const half8*)(hh + (size_t)node*256 + (size_t)(ks & 7)*32 + ((lane >> 4)*8));
            } else {
                const float* pp = param + (size_t)(cbase + 2*m)*64 + (ks - 8)*32 + (lane >> 4)*8;
                float4 p0 = *(const float4*)pp;
                float4 p1 = *(const float4*)(pp + 4);
                A[s][0]=(_Float16)p0.x; A[s][1]=(_Float16)p0.y; A[s][2]=(_Float16)p0.z; A[s][3]=(_Float16)p0.w;
                A[s][4]=(_Float16)p1.x; A[s][5]=(_Float16)p1.y; A[s][6]=(_Float16)p1.z; A[s][7]=(_Float16)p1.w;
            }
        }
        const _Float16* lb = ldsB1 + (ks & 1)*2048;
        #pragma unroll
        for (int tile = 0; tile < 4; ++tile) {
            half8 Bh = *(const half8*)(lb + tile*512 + lane*8);
            #pragma unroll
            for (int s = 0; s < NSUB; ++s)
                acc[s][tile] = mfma16h(A[s], Bh, acc[s][tile]);
        }
        if (hasNext)
            *(half8*)(ldsB1 + ((ks+1) & 1)*2048 + t*8) = stg;
        __syncthreads();
    }

    const float* bias = isV ? bs1 : b1;
    _Float16* o = isV ? V : U;
    #pragma unroll
    for (int s = 0; s < NSUB; ++s) {
        #pragma unroll
        for (int tile = 0; tile < 4; ++tile) {
            int col = cbl*64 + tile*16 + (lane & 15);
            float bv = bias[col];
            #pragma unroll
            for (int r = 0; r < 4; ++r) {
                int m = row0 + (s*4 + w)*16 + (lane >> 4)*4 + r;
                if (m < n)
                    o[(size_t)m*512 + col] = (_Float16)tanhf(acc[s][tile][r] + bv);
            }
        }
    }
}

// ---------------------------------------------------------------------------
// k2 body (dispatch path)
// ---------------------------------------------------------------------------
template<int NSUB>
__device__ __forceinline__ void k2_body(
    int rb, int cb, int start, int n,
    const _Float16* __restrict__ U, const _Float16* __restrict__ V,
    const int* __restrict__ kids,
    const _Float16* __restrict__ w2pk, const _Float16* __restrict__ ws2pk,
    const float* __restrict__ b2, const float* __restrict__ bs2,
    _Float16* __restrict__ hh)
{
    __shared__ __align__(16) _Float16 ldsB2[2*2048];
    const int t = threadIdx.x, lane = t & 63, w = t >> 6;
    const bool isSym = cb >= 4;
    const int cbl = isSym ? cb - 4 : cb;
    const _Float16* pk = (isSym ? ws2pk : w2pk) + (size_t)cbl * 16 * 2048;
    const _Float16* Asrc = isSym ? V : U;
    const int row0 = rb * NSUB * 64;

    f32x4 acc[NSUB][4];
    #pragma unroll
    for (int s = 0; s < NSUB; ++s)
        #pragma unroll
        for (int c = 0; c < 4; ++c) acc[s][c] = (f32x4){0.f,0.f,0.f,0.f};

    *(half8*)(ldsB2 + t*8) = *(const half8*)(pk + (size_t)t*8);
    __syncthreads();

    for (int ks = 0; ks < 16; ++ks) {
        const bool hasNext = ks + 1 < 16;
        half8 stg;
        if (hasNext) stg = *(const half8*)(pk + (size_t)(ks+1)*2048 + (size_t)t*8);
        half8 A[NSUB];
        #pragma unroll
        for (int s = 0; s < NSUB; ++s) {
            int m = row0 + (s*4 + w)*16 + (lane & 15);
            if (m >= n) m = n - 1;
            A[s] = *(const half8*)(Asrc + (size_t)m*512 + (size_t)ks*32 + ((lane >> 4)*8));
        }
        const _Float16* lb = ldsB2 + (ks & 1)*2048;
        #pragma unroll
        for (int tile = 0; tile < 4; ++tile) {
            half8 Bh = *(const half8*)(lb + tile*512 + lane*8);
            #pragma unroll
            for (int s = 0; s < NSUB; ++s)
                acc[s][tile] = mfma16h(A[s], Bh, acc[s][tile]);
        }
        if (hasNext)
            *(half8*)(ldsB2 + ((ks+1) & 1)*2048 + t*8) = stg;
        __syncthreads();
    }

    const float* bias = isSym ? bs2 : b2;
    const int want = isSym ? 1 : 0;
    #pragma unroll
    for (int s = 0; s < NSUB; ++s) {
        #pragma unroll
        for (int tile = 0; tile < 4; ++tile) {
            int col = cbl*64 + tile*16 + (lane & 15);
            float bv = bias[col];
            #pragma unroll
            for (int r = 0; r < 4; ++r) {
                int m = row0 + (s*4 + w)*16 + (lane >> 4)*4 + r;
                if (m < n && kids[3*(start + m) + 2] == want)
                    hh[(size_t)(start + m)*256 + col] = (_Float16)tanhf(acc[s][tile][r] + bv);
            }
        }
    }
}

template<int NSUB>
__global__ __launch_bounds__(256) void k1_kernel(
    const _Float16* __restrict__ hh, const float* __restrict__ param,
    const _Float16* __restrict__ wcatpk, const _Float16* __restrict__ wscatpk,
    const float* __restrict__ b1, const float* __restrict__ bs1,
    _Float16* __restrict__ U, _Float16* __restrict__ V, int start, int n)
{
    k1_body<NSUB>(blockIdx.x, blockIdx.y, start, n, hh, param, wcatpk, wscatpk, b1, bs1, U, V);
}

template<int NSUB>
__global__ __launch_bounds__(256) void k2_kernel(
    const _Float16* __restrict__ U, const _Float16* __restrict__ V,
    const int* __restrict__ kids,
    const _Float16* __restrict__ w2pk, const _Float16* __restrict__ ws2pk,
    const float* __restrict__ b2, const float* __restrict__ bs2,
    _Float16* __restrict__ hh, int start, int n)
{
    k2_body<NSUB>(blockIdx.x, blockIdx.y, start, n, U, V, kids, w2pk, ws2pk, b2, bs2, hh);
}

// ---------------------------------------------------------------------------
// Tail bodies: weights in LDS; PLAIN cached loads (L2 stays warm — no acquire
// invalidation in this design); A-fragments preloaded to registers for ILP.
// ---------------------------------------------------------------------------
__device__ __forceinline__ void k1_tail(
    int rb, int cb, int start, int n,
    const _Float16* __restrict__ hh, const float* __restrict__ param,
    const _Float16* wlds, f32x4 bv,
    _Float16* __restrict__ U, _Float16* __restrict__ V)
{
    const int t = threadIdx.x, lane = t & 63, w = t >> 6;
    const bool isV = cb >= 8;
    const int cbl = isV ? cb - 8 : cb;
    const int row0  = rb * 64;
    const int cbase = 2 * (start - LEAF);

    int m = row0 + w*16 + (lane & 15);
    if (m >= n) m = n - 1;

    f32x4 acc[4];
    #pragma unroll
    for (int c = 0; c < 4; ++c) acc[c] = (f32x4){0.f,0.f,0.f,0.f};

    if (!isV) {
        half8 A[16];
        #pragma unroll
        for (int ks = 0; ks < 16; ++ks) {
            int node = cbase + 2*m + (ks >= 8 ? 1 : 0);
            A[ks] = *(const half8*)(hh + (size_t)node*256 + (size_t)(ks & 7)*32 + ((lane >> 4)*8));
        }
        #pragma unroll
        for (int ks = 0; ks < 16; ++ks) {
            const _Float16* lb = wlds + ks*2048;
            #pragma unroll
            for (int tile = 0; tile < 4; ++tile) {
                half8 Bh = *(const half8*)(lb + tile*512 + lane*8);
                acc[tile] = mfma16h(A[ks], Bh, acc[tile]);
            }
        }
    } else {
        half8 A[10];
        #pragma unroll
        for (int ks = 0; ks < 8; ++ks)
            A[ks] = *(const half8*)(hh + (size_t)(cbase + 2*m)*256 + (size_t)ks*32 + ((lane >> 4)*8));
        #pragma unroll
        for (int ks = 8; ks < 10; ++ks) {
            const float* pp = param + (size_t)(cbase + 2*m)*64 + (ks - 8)*32 + (lane >> 4)*8;
            float4 p0 = *(const float4*)pp;
            float4 p1 = *(const float4*)(pp + 4);
            A[ks][0]=(_Float16)p0.x; A[ks][1]=(_Float16)p0.y; A[ks][2]=(_Float16)p0.z; A[ks][3]=(_Float16)p0.w;
            A[ks][4]=(_Float16)p1.x; A[ks][5]=(_Float16)p1.y; A[ks][6]=(_Float16)p1.z; A[ks][7]=(_Float16)p1.w;
        }
        #pragma unroll
        for (int ks = 0; ks < 10; ++ks) {
            const _Float16* lb = wlds + ks*2048;
            #pragma unroll
            for (int tile = 0; tile < 4; ++tile) {
                half8 Bh = *(const half8*)(lb + tile*512 + lane*8);
                acc[tile] = mfma16h(A[ks], Bh, acc[tile]);
            }
        }
    }

    _Float16* o = isV ? V : U;
    #pragma unroll
    for (int tile = 0; tile < 4; ++tile) {
        int col = cbl*64 + tile*16 + (lane & 15);
        #pragma unroll
        for (int r = 0; r < 4; ++r) {
            int mm = row0 + w*16 + (lane >> 4)*4 + r;
            if (mm < n)
                o[(size_t)mm*512 + col] = (_Float16)tanhf(acc[tile][r] + bv[tile]);
        }
    }
}

__device__ __forceinline__ void k2_tail(
    int rb, int cb, int start, int n,
    const _Float16* __restrict__ U, const _Float16* __restrict__ V,
    const int* __restrict__ kids,
    const _Float16* wlds, f32x4 bv,
    _Float16* __restrict__ hh)
{
    const int t = threadIdx.x, lane = t & 63, w = t >> 6;
    const bool isSym = cb >= 4;
    const int cbl = isSym ? cb - 4 : cb;
    const _Float16* Asrc = isSym ? V : U;
    const int row0 = rb * 64;

    int m = row0 + w*16 + (lane & 15);
    if (m >= n) m = n - 1;

    half8 A[16];
    #pragma unroll
    for (int ks = 0; ks < 16; ++ks)
        A[ks] = *(const half8*)(Asrc + (size_t)m*512 + (size_t)ks*32 + ((lane >> 4)*8));

    f32x4 acc[4];
    #pragma unroll
    for (int c = 0; c < 4; ++c) acc[c] = (f32x4){0.f,0.f,0.f,0.f};
    #pragma unroll
    for (int ks = 0; ks < 16; ++ks) {
        const _Float16* lb = wlds + ks*2048;
        #pragma unroll
        for (int tile = 0; tile < 4; ++tile) {
            half8 Bh = *(const half8*)(lb + tile*512 + lane*8);
            acc[tile] = mfma16h(A[ks], Bh, acc[tile]);
        }
    }

    const int want = isSym ? 1 : 0;
    #pragma unroll
    for (int tile = 0; tile < 4; ++tile) {
        int col = cbl*64 + tile*16 + (lane & 15);
        #pragma unroll
        for (int r = 0; r < 4; ++r) {
            int mm = row0 + w*16 + (lane >> 4)*4 + r;
            if (mm < n && kids[3*(start + mm) + 2] == want)
                hh[(size_t)(start + mm)*256 + col] = (_Float16)tanhf(acc[tile][r] + bv[tile]);
        }
    }
}

// ---------------------------------------------------------------------------
// Flag barrier: writers release-store (waitcnt+wbl2 -> LLC), non-writers
// relaxed store. NO acquire-inv: every cross-phase address is written exactly
// once per run and only read after the writer's release (first-touch in the
// reader's L2 pulls fresh data from LLC). Workgroup fence = ordering only.
// ---------------------------------------------------------------------------
#define TAILG 48
__device__ __forceinline__ void fbar(unsigned* flags, unsigned tgt, bool wrote)
{
    __syncthreads();
    if (threadIdx.x == 0) {
        if (wrote)
            __hip_atomic_store(flags + blockIdx.x*16, tgt, __ATOMIC_RELEASE, __HIP_MEMORY_SCOPE_AGENT);
        else
            __hip_atomic_store(flags + blockIdx.x*16, tgt, __ATOMIC_RELAXED, __HIP_MEMORY_SCOPE_AGENT);
    }
    if (threadIdx.x < TAILG) {
        while (__hip_atomic_load(flags + threadIdx.x*16, __ATOMIC_RELAXED, __HIP_MEMORY_SCOPE_AGENT) < tgt)
            __builtin_amdgcn_s_sleep(1);
    }
    __syncthreads();
    __builtin_amdgcn_fence(__ATOMIC_ACQUIRE, "workgroup");
}

// ---------------------------------------------------------------------------
// Tail: levels n<=512 persistent, 48 blocks.
// Blocks 0-31: k1 (16 col-slices x 2 row-halves). 32-47: k2 (8 x 2).
// U/V get a DISJOINT slice per level (base = 1024-2n rows) so no address is
// ever re-used -> stale-L2 hazard eliminated without acquire-inv.
// ---------------------------------------------------------------------------
__global__ __launch_bounds__(256) void tail_kernel(
    _Float16* __restrict__ hh, const float* __restrict__ param,
    const _Float16* __restrict__ wcatpk, const _Float16* __restrict__ wscatpk,
    const float* __restrict__ b1, const float* __restrict__ bs1,
    _Float16* __restrict__ U, _Float16* __restrict__ V,
    const int* __restrict__ kids,
    const _Float16* __restrict__ w2pk, const _Float16* __restrict__ ws2pk,
    const float* __restrict__ b2, const float* __restrict__ bs2,
    unsigned* __restrict__ flags, float* __restrict__ out)
{
    __shared__ __align__(16) _Float16 wlds[16*2048];   // 64 KB
    const int b = blockIdx.x;          // 0..47
    const int t = threadIdx.x, lane = t & 63;
    const bool isK1 = b < 32;
    int cb, rh;
    const _Float16* src;
    const float* bias;
    int nh;
    if (isK1) {
        cb = b & 15; rh = b >> 4;
        if (cb < 8) { src = wcatpk  + (size_t)cb*16*2048;     nh = 16*256; bias = b1; }
        else        { src = wscatpk + (size_t)(cb-8)*10*2048; nh = 10*256; bias = bs1; }
    } else {
        int i = b - 32; cb = i & 7; rh = i >> 3;
        if (cb < 4) { src = w2pk  + (size_t)cb*16*2048;     bias = b2; }
        else        { src = ws2pk + (size_t)(cb-4)*16*2048; bias = bs2; }
        nh = 16*256;
    }
    for (int i = t; i < nh; i += 256)
        *(half8*)(wlds + (size_t)i*8) = *(const half8*)(src + (size_t)i*8);

    f32x4 bv;
    {
        int cbl = isK1 ? (cb & 7) : (cb & 3);
        #pragma unroll
        for (int tile = 0; tile < 4; ++tile)
            bv[tile] = bias[cbl*64 + tile*16 + (lane & 15)];
    }
    __syncthreads();

    unsigned tgt = 0;
    int start = LEAF + 8192 + 4096 + 2048 + 1024;   // 31744, first tail level n=512
    for (int n = 512; n >= 1; n >>= 1) {
        _Float16* Ut = U + (size_t)(1024 - 2*n)*512;
        _Float16* Vt = V + (size_t)(1024 - 2*n)*512;
        int rt = (n + 63) >> 6;
        if (isK1) {
            for (int r = rh; r < rt; r += 2)
                k1_tail(r, cb, start, n, hh, param, wlds, bv, Ut, Vt);
        }
        ++tgt; fbar(flags, tgt, isK1);
        if (!isK1) {
            for (int r = rh; r < rt; r += 2)
                k2_tail(r, cb, start, n, Ut, Vt, kids, wlds, bv, hh);
        }
        ++tgt; fbar(flags, tgt, !isK1);
        start += n;
    }
    if (b == 0)
        out[t] = (float)hh[(size_t)(NNODE - 1)*256 + t];
}

extern "C" void kernel_launch(void* const* d_in, const int* in_sizes, int n_in,
                              void* d_out, int out_size, void* d_ws, size_t ws_size,
                              hipStream_t stream) {
    const int*   kids  = (const int*)  d_in[0];
    const float* shape = (const float*)d_in[1];
    const float* param = (const float*)d_in[2];
    const float* Wb    = (const float*)d_in[3];
    const float* bb    = (const float*)d_in[4];
    const float* Wl    = (const float*)d_in[5];
    const float* Wr    = (const float*)d_in[6];
    const float* b1    = (const float*)d_in[7];
    const float* W2    = (const float*)d_in[8];
    const float* b2    = (const float*)d_in[9];
    const float* Wsl   = (const float*)d_in[10];
    const float* Wsr   = (const float*)d_in[11];
    const float* bs1   = (const float*)d_in[12];
    const float* Ws2   = (const float*)d_in[13];
    const float* bs2   = (const float*)d_in[14];
    float* out = (float*)d_out;

    char* ws = (char*)d_ws;
    _Float16* hh      = (_Float16*)(ws + 0);          // 16.8MB
    _Float16* U       = (_Float16*)(ws + 16777216);   // 8.4MB
    _Float16* V       = (_Float16*)(ws + 25165824);   // 8.4MB
    _Float16* wcatpk  = (_Float16*)(ws + 33554432);   // 512KB
    _Float16* wscatpk = (_Float16*)(ws + 34078720);   // 320KB
    _Float16* w2pk    = (_Float16*)(ws + 34406400);   // 256KB
    _Float16* ws2pk   = (_Float16*)(ws + 34668544);   // 256KB
    _Float16* wbpk    = (_Float16*)(ws + 34930688);   // 64KB
    unsigned* flags   = (unsigned*)(ws + 34996224);   // 48*64B

    hipMemsetAsync(flags, 0, TAILG*64, stream);

    pack_all<<<2816, 256, 0, stream>>>(Wl, Wr, Wsl, Wsr, W2, Ws2, Wb,
                                       wcatpk, wscatpk, w2pk, ws2pk, wbpk);

    leaf_mfma_kernel<<<LEAF/64, 256, 0, stream>>>(shape, wbpk, bb, hh);

    int start = LEAF;
    for (int n = 8192; n >= 1024; n >>= 1) {
        if (n == 8192) {
            k1_kernel<2><<<dim3(n/128, 16), 256, 0, stream>>>(hh, param, wcatpk, wscatpk,
                                                              b1, bs1, U, V, start, n);
        } else {
            k1_kernel<1><<<dim3(n/64, 16), 256, 0, stream>>>(hh, param, wcatpk, wscatpk,
                                                             b1, bs1, U, V, start, n);
        }
        k2_kernel<1><<<dim3(n/64, 8), 256, 0, stream>>>(U, V, kids, w2pk, ws2pk,
                                                        b2, bs2, hh, start, n);
        start += n;
    }

    tail_kernel<<<TAILG, 256, 0, stream>>>(hh, param, wcatpk, wscatpk, b1, bs1,
                                           U, V, kids, w2pk, ws2pk, b2, bs2, flags, out);
}